// Round 1
// baseline (109.570 us; speedup 1.0000x reference)
//
#include <hip/hip_runtime.h>

#define NVOX   129600          // 60*36*60
#define NCH    512
#define IMH    120             // 480/4
#define IMW    160             // 640/4
#define GROUPS (NVOX / 4)      // 32400 float4 groups per channel
#define CHPT   8               // channels per thread
#define CGRP   (NCH / CHPT)    // 64 channel groups

__global__ __launch_bounds__(256) void proj2d3d_kernel(
    const float* __restrict__ x2d,
    const float* __restrict__ pose,     // inv_cam_pose, 4x4 row-major
    const float* __restrict__ origin,   // vox_origin, 3
    const float* __restrict__ camk,     // cam_k, 3x3 row-major
    const int*   __restrict__ fliplr,
    float*       __restrict__ out)
{
    long tid = (long)blockIdx.x * blockDim.x + threadIdx.x;
    int g  = (int)(tid % GROUPS);   // voxel group -> v0 = 4*g
    int cg = (int)(tid / GROUPS);   // channel group
    if (cg >= CGRP) return;
    int v0 = g * 4;

    float o0 = origin[0], o1 = origin[1], o2 = origin[2];
    int flip = fliplr[0];

    int lin[4];
#pragma unroll
    for (int i = 0; i < 4; ++i) {
        int v  = v0 + i;
        int gx = v / 2160;          // SCENE[1]*SCENE[2] = 36*60
        int r  = v - gx * 2160;
        int gy = r / 60;
        int gz = r - gy * 60;
        // world coords: note reference swaps y/z axes of the voxel grid
        float wx = gx * 0.08f + 0.04f + o0;
        float wy = gz * 0.08f + 0.04f + o1;
        float wz = gy * 0.08f + 0.04f + o2;
        // camera: pts_cam = inv_cam_pose @ [w,1]
        float cx = pose[0]*wx + pose[1]*wy + pose[2]*wz  + pose[3];
        float cy = pose[4]*wx + pose[5]*wy + pose[6]*wz  + pose[7];
        float cz = pose[8]*wx + pose[9]*wy + pose[10]*wz + pose[11];
        // image: pts_img = cam_k @ pts_cam[:3]
        float ix = camk[0]*cx + camk[1]*cy + camk[2]*cz;
        float iy = camk[3]*cx + camk[4]*cy + camk[5]*cz;
        float iz = camk[6]*cx + camk[7]*cy + camk[8]*cz;
        float u  = rintf(ix / iz);   // round half-to-even == jnp.round
        float vv = rintf(iy / iz);
        bool ok = (cz > 0.0f) && (u >= 0.0f) && (u < 640.0f)
                              && (vv >= 0.0f) && (vv < 480.0f);
        int l = -1;
        if (ok) {
            float colf = flip ? (639.0f - u) : u;
            int row = (int)vv   >> 2;   // floor(row/4), row >= 0
            int col = (int)colf >> 2;   // floor(col/4), col >= 0
            l = row * IMW + col;
        }
        lin[i] = l;
    }

    int ch0 = cg * CHPT;
#pragma unroll
    for (int cc = 0; cc < CHPT; ++cc) {
        int ch = ch0 + cc;
        const float* s = x2d + (size_t)ch * (IMH * IMW);
        float4 o;
        o.x = (lin[0] >= 0) ? s[lin[0]] : 0.0f;
        o.y = (lin[1] >= 0) ? s[lin[1]] : 0.0f;
        o.z = (lin[2] >= 0) ? s[lin[2]] : 0.0f;
        o.w = (lin[3] >= 0) ? s[lin[3]] : 0.0f;
        *reinterpret_cast<float4*>(out + (size_t)ch * NVOX + v0) = o;
    }
}

extern "C" void kernel_launch(void* const* d_in, const int* in_sizes, int n_in,
                              void* d_out, int out_size, void* d_ws, size_t ws_size,
                              hipStream_t stream) {
    const float* x2d    = (const float*)d_in[0];
    const float* pose   = (const float*)d_in[1];
    const float* origin = (const float*)d_in[2];
    const float* camk   = (const float*)d_in[3];
    // d_in[4], d_in[5] (old_voxel_indices / old_image_indices) are unused by the reference
    const int*   flip   = (const int*)d_in[6];
    float*       out    = (float*)d_out;

    long total = (long)CGRP * GROUPS;          // 64 * 32400 = 2,073,600 threads
    int  block = 256;
    unsigned grid = (unsigned)((total + block - 1) / block);   // 8100 blocks
    proj2d3d_kernel<<<dim3(grid), dim3(block), 0, stream>>>(
        x2d, pose, origin, camk, flip, out);
}

// Round 2
// 70.163 us; speedup vs baseline: 1.5616x; 1.5616x over previous
//
#include <hip/hip_runtime.h>

#define NVOX 129600            // 60*36*60
#define NCH  512
#define NPIX 19200             // 120*160
#define IMW  160

// ---------- pass 1: transpose x2d (512, 19200) -> xT (19200, 512) ----------
__global__ __launch_bounds__(256) void transpose_kernel(
    const float* __restrict__ x2d, float* __restrict__ xT)
{
    __shared__ float tile[64][65];
    int p0 = blockIdx.x * 64;          // pixel tile base
    int c0 = blockIdx.y * 64;          // channel tile base
    int t  = threadIdx.x;
    int a  = t & 15;                   // float4 slot (16 per 64)
    int bq = t >> 4;                   // 0..15

    const float4* src4 = reinterpret_cast<const float4*>(x2d);
#pragma unroll
    for (int i = 0; i < 4; ++i) {
        int c = bq + i * 16;           // channel row within tile
        float4 v = src4[((size_t)(c0 + c) * NPIX + p0) / 4 + a];
        tile[a * 4 + 0][c] = v.x;
        tile[a * 4 + 1][c] = v.y;
        tile[a * 4 + 2][c] = v.z;
        tile[a * 4 + 3][c] = v.w;
    }
    __syncthreads();
    float4* dst4 = reinterpret_cast<float4*>(xT);
#pragma unroll
    for (int i = 0; i < 4; ++i) {
        int p = bq + i * 16;           // pixel row within tile
        float4 v;
        v.x = tile[p][a * 4 + 0];
        v.y = tile[p][a * 4 + 1];
        v.z = tile[p][a * 4 + 2];
        v.w = tile[p][a * 4 + 3];
        dst4[((size_t)(p0 + p) * NCH + c0) / 4 + a] = v;
    }
}

// ---------- pass 2: per-voxel gather from xT, coalesced stores ----------
// block: 64 voxels x 128 channels, 512 threads. LDS tile [64][130] (pad).
__global__ __launch_bounds__(512) void gather_kernel(
    const float* __restrict__ xT,
    const float* __restrict__ pose,
    const float* __restrict__ origin,
    const float* __restrict__ camk,
    const int*   __restrict__ fliplr,
    float*       __restrict__ out)
{
    __shared__ float lds[64 * 130];
    __shared__ int   lin_s[64];

    int b    = blockIdx.x;
    int q    = b & 3;                  // channel quarter
    int vb   = b >> 2;                 // voxel block
    int v0   = vb * 64;
    int c0   = q * 128;
    int t    = threadIdx.x;
    int wv   = t >> 6;                 // wave id 0..7
    int lane = t & 63;

    if (t < 64) {                      // projection for this block's 64 voxels
        int v  = v0 + t;
        int gx = v / 2160;             // 36*60
        int r  = v - gx * 2160;
        int gy = r / 60;
        int gz = r - gy * 60;
        float wx = gx * 0.08f + 0.04f + origin[0];
        float wy = gz * 0.08f + 0.04f + origin[1];
        float wz = gy * 0.08f + 0.04f + origin[2];
        float cx = pose[0]*wx + pose[1]*wy + pose[2]*wz  + pose[3];
        float cy = pose[4]*wx + pose[5]*wy + pose[6]*wz  + pose[7];
        float cz = pose[8]*wx + pose[9]*wy + pose[10]*wz + pose[11];
        float ix = camk[0]*cx + camk[1]*cy + camk[2]*cz;
        float iy = camk[3]*cx + camk[4]*cy + camk[5]*cz;
        float iz = camk[6]*cx + camk[7]*cy + camk[8]*cz;
        float u  = rintf(ix / iz);     // round half-to-even == jnp.round
        float vv = rintf(iy / iz);
        bool ok = (cz > 0.0f) && (u >= 0.0f) && (u < 640.0f)
                              && (vv >= 0.0f) && (vv < 480.0f);
        int l = -1;
        if (ok) {
            float colf = fliplr[0] ? (639.0f - u) : u;
            l = (((int)vv) >> 2) * IMW + (((int)colf) >> 2);
        }
        lin_s[t] = l;
    }
    __syncthreads();

    // load: wave wv stages rows w = wv*8..+8; lane = channel (contiguous)
#pragma unroll
    for (int k = 0; k < 8; ++k) {
        int w = wv * 8 + k;
        int l = lin_s[w];              // wave-uniform
        if (l >= 0) {
            const float2* src = reinterpret_cast<const float2*>(
                xT + (size_t)l * NCH + c0);
            float2 val = src[lane];    // 512B coalesced per wave
            *reinterpret_cast<float2*>(&lds[w * 130 + lane * 2]) = val;
        }
    }
    __syncthreads();

    // store: lane = voxel (coalesced), wave wv covers 16 channels
    int  myl   = lin_s[lane];
    bool valid = myl >= 0;
    float* obase = out + (size_t)c0 * NVOX + v0 + lane;
#pragma unroll
    for (int i = 0; i < 16; ++i) {
        int cc = wv * 16 + i;
        float val = valid ? lds[lane * 130 + cc] : 0.0f;
        obase[(size_t)cc * NVOX] = val;
    }
}

// ---------- fallback (round-1 kernel) if d_ws is too small ----------
__global__ __launch_bounds__(256) void fused_kernel(
    const float* __restrict__ x2d, const float* __restrict__ pose,
    const float* __restrict__ origin, const float* __restrict__ camk,
    const int* __restrict__ fliplr, float* __restrict__ out)
{
    long tid = (long)blockIdx.x * blockDim.x + threadIdx.x;
    int g  = (int)(tid % 32400);
    int cg = (int)(tid / 32400);
    if (cg >= 64) return;
    int v0 = g * 4;
    int lin[4];
#pragma unroll
    for (int i = 0; i < 4; ++i) {
        int v = v0 + i;
        int gx = v / 2160; int r = v - gx * 2160;
        int gy = r / 60;   int gz = r - gy * 60;
        float wx = gx * 0.08f + 0.04f + origin[0];
        float wy = gz * 0.08f + 0.04f + origin[1];
        float wz = gy * 0.08f + 0.04f + origin[2];
        float cx = pose[0]*wx + pose[1]*wy + pose[2]*wz  + pose[3];
        float cy = pose[4]*wx + pose[5]*wy + pose[6]*wz  + pose[7];
        float cz = pose[8]*wx + pose[9]*wy + pose[10]*wz + pose[11];
        float ix = camk[0]*cx + camk[1]*cy + camk[2]*cz;
        float iy = camk[3]*cx + camk[4]*cy + camk[5]*cz;
        float iz = camk[6]*cx + camk[7]*cy + camk[8]*cz;
        float u  = rintf(ix / iz);
        float vv = rintf(iy / iz);
        bool ok = (cz > 0.0f) && (u >= 0.0f) && (u < 640.0f)
                              && (vv >= 0.0f) && (vv < 480.0f);
        int l = -1;
        if (ok) {
            float colf = fliplr[0] ? (639.0f - u) : u;
            l = (((int)vv) >> 2) * IMW + (((int)colf) >> 2);
        }
        lin[i] = l;
    }
    int ch0 = cg * 8;
#pragma unroll
    for (int cc = 0; cc < 8; ++cc) {
        int ch = ch0 + cc;
        const float* s = x2d + (size_t)ch * NPIX;
        float4 o;
        o.x = (lin[0] >= 0) ? s[lin[0]] : 0.0f;
        o.y = (lin[1] >= 0) ? s[lin[1]] : 0.0f;
        o.z = (lin[2] >= 0) ? s[lin[2]] : 0.0f;
        o.w = (lin[3] >= 0) ? s[lin[3]] : 0.0f;
        *reinterpret_cast<float4*>(out + (size_t)ch * NVOX + v0) = o;
    }
}

extern "C" void kernel_launch(void* const* d_in, const int* in_sizes, int n_in,
                              void* d_out, int out_size, void* d_ws, size_t ws_size,
                              hipStream_t stream) {
    const float* x2d    = (const float*)d_in[0];
    const float* pose   = (const float*)d_in[1];
    const float* origin = (const float*)d_in[2];
    const float* camk   = (const float*)d_in[3];
    const int*   flip   = (const int*)d_in[6];
    float*       out    = (float*)d_out;

    const size_t xT_bytes = (size_t)NPIX * NCH * sizeof(float);   // 39.3 MB
    if (ws_size >= xT_bytes) {
        float* xT = (float*)d_ws;
        transpose_kernel<<<dim3(NPIX / 64, NCH / 64), dim3(256), 0, stream>>>(x2d, xT);
        gather_kernel<<<dim3((NVOX / 64) * 4), dim3(512), 0, stream>>>(
            xT, pose, origin, camk, flip, out);
    } else {
        fused_kernel<<<dim3(8100), dim3(256), 0, stream>>>(
            x2d, pose, origin, camk, flip, out);
    }
}

// Round 3
// 68.286 us; speedup vs baseline: 1.6046x; 1.0275x over previous
//
#include <hip/hip_runtime.h>

#define NVOX 129600            // 60*36*60
#define NCH  512
#define NPIX 19200             // 120*160
#define IMW  160

// ---------- pass 1: transpose x2d (512, 19200) -> xT (19200, 512) ----------
// xT writes stay CACHED (gather re-reads them from L3).
__global__ __launch_bounds__(256) void transpose_kernel(
    const float* __restrict__ x2d, float* __restrict__ xT)
{
    __shared__ float tile[64][65];
    int p0 = blockIdx.x * 64;          // pixel tile base
    int c0 = blockIdx.y * 64;          // channel tile base
    int t  = threadIdx.x;
    int a  = t & 15;                   // float4 slot (16 per 64)
    int bq = t >> 4;                   // 0..15

    const float4* src4 = reinterpret_cast<const float4*>(x2d);
#pragma unroll
    for (int i = 0; i < 4; ++i) {
        int c = bq + i * 16;           // channel row within tile
        float4 v = src4[((size_t)(c0 + c) * NPIX + p0) / 4 + a];
        tile[a * 4 + 0][c] = v.x;
        tile[a * 4 + 1][c] = v.y;
        tile[a * 4 + 2][c] = v.z;
        tile[a * 4 + 3][c] = v.w;
    }
    __syncthreads();
    float4* dst4 = reinterpret_cast<float4*>(xT);
#pragma unroll
    for (int i = 0; i < 4; ++i) {
        int p = bq + i * 16;           // pixel row within tile
        float4 v;
        v.x = tile[p][a * 4 + 0];
        v.y = tile[p][a * 4 + 1];
        v.z = tile[p][a * 4 + 2];
        v.w = tile[p][a * 4 + 3];
        dst4[((size_t)(p0 + p) * NCH + c0) / 4 + a] = v;
    }
}

// ---------- pass 2: per-voxel gather from xT, coalesced NT stores ----------
// block: 64 voxels x 128 channels, 512 threads. LDS tile [64][130] (pad).
__global__ __launch_bounds__(512) void gather_kernel(
    const float* __restrict__ xT,
    const float* __restrict__ pose,
    const float* __restrict__ origin,
    const float* __restrict__ camk,
    const int*   __restrict__ fliplr,
    float*       __restrict__ out)
{
    __shared__ float lds[64 * 130];
    __shared__ int   lin_s[64];

    int b    = blockIdx.x;
    int q    = b & 3;                  // channel quarter
    int vb   = b >> 2;                 // voxel block
    int v0   = vb * 64;
    int c0   = q * 128;
    int t    = threadIdx.x;
    int wv   = t >> 6;                 // wave id 0..7
    int lane = t & 63;

    if (t < 64) {                      // projection for this block's 64 voxels
        int v  = v0 + t;
        int gx = v / 2160;             // 36*60
        int r  = v - gx * 2160;
        int gy = r / 60;
        int gz = r - gy * 60;
        float wx = gx * 0.08f + 0.04f + origin[0];
        float wy = gz * 0.08f + 0.04f + origin[1];
        float wz = gy * 0.08f + 0.04f + origin[2];
        float cx = pose[0]*wx + pose[1]*wy + pose[2]*wz  + pose[3];
        float cy = pose[4]*wx + pose[5]*wy + pose[6]*wz  + pose[7];
        float cz = pose[8]*wx + pose[9]*wy + pose[10]*wz + pose[11];
        float ix = camk[0]*cx + camk[1]*cy + camk[2]*cz;
        float iy = camk[3]*cx + camk[4]*cy + camk[5]*cz;
        float iz = camk[6]*cx + camk[7]*cy + camk[8]*cz;
        float u  = rintf(ix / iz);     // round half-to-even == jnp.round
        float vv = rintf(iy / iz);
        bool ok = (cz > 0.0f) && (u >= 0.0f) && (u < 640.0f)
                              && (vv >= 0.0f) && (vv < 480.0f);
        int l = -1;
        if (ok) {
            float colf = fliplr[0] ? (639.0f - u) : u;
            l = (((int)vv) >> 2) * IMW + (((int)colf) >> 2);
        }
        lin_s[t] = l;
    }
    __syncthreads();

    // load: wave wv stages rows w = wv*8..+8; lane = channel (contiguous)
#pragma unroll
    for (int k = 0; k < 8; ++k) {
        int w = wv * 8 + k;
        int l = lin_s[w];              // wave-uniform
        if (l >= 0) {
            const float2* src = reinterpret_cast<const float2*>(
                xT + (size_t)l * NCH + c0);
            float2 val = src[lane];    // 512B coalesced per wave
            *reinterpret_cast<float2*>(&lds[w * 130 + lane * 2]) = val;
        }
    }
    __syncthreads();

    // store: lane = voxel (coalesced), wave wv covers 16 channels.
    // Nontemporal: out is write-once, keep it out of L2/L3 so xT stays hot.
    int  myl   = lin_s[lane];
    bool valid = myl >= 0;
    float* obase = out + (size_t)c0 * NVOX + v0 + lane;
#pragma unroll
    for (int i = 0; i < 16; ++i) {
        int cc = wv * 16 + i;
        float val = valid ? lds[lane * 130 + cc] : 0.0f;
        __builtin_nontemporal_store(val, &obase[(size_t)cc * NVOX]);
    }
}

// ---------- fallback (round-1 kernel) if d_ws is too small ----------
__global__ __launch_bounds__(256) void fused_kernel(
    const float* __restrict__ x2d, const float* __restrict__ pose,
    const float* __restrict__ origin, const float* __restrict__ camk,
    const int* __restrict__ fliplr, float* __restrict__ out)
{
    long tid = (long)blockIdx.x * blockDim.x + threadIdx.x;
    int g  = (int)(tid % 32400);
    int cg = (int)(tid / 32400);
    if (cg >= 64) return;
    int v0 = g * 4;
    int lin[4];
#pragma unroll
    for (int i = 0; i < 4; ++i) {
        int v = v0 + i;
        int gx = v / 2160; int r = v - gx * 2160;
        int gy = r / 60;   int gz = r - gy * 60;
        float wx = gx * 0.08f + 0.04f + origin[0];
        float wy = gz * 0.08f + 0.04f + origin[1];
        float wz = gy * 0.08f + 0.04f + origin[2];
        float cx = pose[0]*wx + pose[1]*wy + pose[2]*wz  + pose[3];
        float cy = pose[4]*wx + pose[5]*wy + pose[6]*wz  + pose[7];
        float cz = pose[8]*wx + pose[9]*wy + pose[10]*wz + pose[11];
        float ix = camk[0]*cx + camk[1]*cy + camk[2]*cz;
        float iy = camk[3]*cx + camk[4]*cy + camk[5]*cz;
        float iz = camk[6]*cx + camk[7]*cy + camk[8]*cz;
        float u  = rintf(ix / iz);
        float vv = rintf(iy / iz);
        bool ok = (cz > 0.0f) && (u >= 0.0f) && (u < 640.0f)
                              && (vv >= 0.0f) && (vv < 480.0f);
        int l = -1;
        if (ok) {
            float colf = fliplr[0] ? (639.0f - u) : u;
            l = (((int)vv) >> 2) * IMW + (((int)colf) >> 2);
        }
        lin[i] = l;
    }
    int ch0 = cg * 8;
#pragma unroll
    for (int cc = 0; cc < 8; ++cc) {
        int ch = ch0 + cc;
        const float* s = x2d + (size_t)ch * NPIX;
        float4 o;
        o.x = (lin[0] >= 0) ? s[lin[0]] : 0.0f;
        o.y = (lin[1] >= 0) ? s[lin[1]] : 0.0f;
        o.z = (lin[2] >= 0) ? s[lin[2]] : 0.0f;
        o.w = (lin[3] >= 0) ? s[lin[3]] : 0.0f;
        *reinterpret_cast<float4*>(out + (size_t)ch * NVOX + v0) = o;
    }
}

extern "C" void kernel_launch(void* const* d_in, const int* in_sizes, int n_in,
                              void* d_out, int out_size, void* d_ws, size_t ws_size,
                              hipStream_t stream) {
    const float* x2d    = (const float*)d_in[0];
    const float* pose   = (const float*)d_in[1];
    const float* origin = (const float*)d_in[2];
    const float* camk   = (const float*)d_in[3];
    const int*   flip   = (const int*)d_in[6];
    float*       out    = (float*)d_out;

    const size_t xT_bytes = (size_t)NPIX * NCH * sizeof(float);   // 39.3 MB
    if (ws_size >= xT_bytes) {
        float* xT = (float*)d_ws;
        transpose_kernel<<<dim3(NPIX / 64, NCH / 64), dim3(256), 0, stream>>>(x2d, xT);
        gather_kernel<<<dim3((NVOX / 64) * 4), dim3(512), 0, stream>>>(
            xT, pose, origin, camk, flip, out);
    } else {
        fused_kernel<<<dim3(8100), dim3(256), 0, stream>>>(
            x2d, pose, origin, camk, flip, out);
    }
}